// Round 1
// baseline (180.359 us; speedup 1.0000x reference)
//
#include <hip/hip_runtime.h>

#define NNODES 10000
#define MP 10112            // 316 * 32 GEMM M-tiles
#define F 256
#define H 512
#define CAP 128             // bucket capacity; Poisson(32) tail @128 ~ 1e-40
#define H1STR 520           // LDS h1 row stride (f16): 1040 B -> bank-adv 4 -> 2-way (free)
#define ZROW NNODES         // index of the dedicated all-zero row

typedef _Float16 half8 __attribute__((ext_vector_type(8)));
typedef float floatx4 __attribute__((ext_vector_type(4)));
typedef float floatx8 __attribute__((ext_vector_type(8)));

// ---------- zero degree counters (build_k needs cnt=0 before atomics) ----------
__global__ __launch_bounds__(256) void zero_k(int* __restrict__ cnt) {
  int gt = blockIdx.x * 256 + threadIdx.x;
  if (gt < NNODES) cnt[gt] = 0;
}

// ---------- bucket CSR build: one pass, cnt ends as degree ----------
__global__ __launch_bounds__(256) void build_k(const int* __restrict__ src,
                                               const int* __restrict__ dst,
                                               int* __restrict__ cnt,
                                               int* __restrict__ csr, int E) {
  int e = blockIdx.x * blockDim.x + threadIdx.x;
  if (e < E) {
    int d = dst[e];
    int p = atomicAdd(&cnt[d], 1);
    if (p < CAP) csr[(size_t)d * CAP + p] = src[e];
  }
}

// ---------- prep: W1^T + W2^T + xh' = dinv*x (f16) + dinv[] + zero row ----------
// Runs AFTER build_k so degrees are known; folding dinv[src] into the stored
// rows makes the aggregation inner loop a pure unweighted gather-add.
__global__ __launch_bounds__(256) void prep_k(const float* __restrict__ W1,
                                              const float* __restrict__ W2,
                                              const float* __restrict__ x,
                                              const int* __restrict__ cnt,
                                              _Float16* __restrict__ W1t,
                                              _Float16* __restrict__ W2t,
                                              _Float16* __restrict__ xh,
                                              float* __restrict__ dinv) {
  int gt = blockIdx.x * 256 + threadIdx.x;
  if (gt < NNODES) dinv[gt] = rsqrtf((float)(cnt[gt] + 1));
  if (gt < H * F) {
    // W1 (256x512) -> W1t (512x256): gt = n*256+k
    W1t[gt] = (_Float16)W1[(gt & 255) * H + (gt >> 8)];
    // W2 (512x256) -> W2t (256x512): gt = n*512+k
    W2t[gt] = (_Float16)W2[(gt & 511) * F + (gt >> 9)];
  }
  if (gt < NNODES * F / 8) {
    int row = gt >> 5;
    float di = rsqrtf((float)(cnt[row] + 1));
    floatx8 v = *(const floatx8*)(x + (size_t)gt * 8);
    #pragma unroll
    for (int t = 0; t < 8; t++) v[t] *= di;
    *(half8*)(xh + (size_t)gt * 8) = __builtin_convertvector(v, half8);
  }
  if (gt < F / 8) {
    half8 z = {};
    *(half8*)(xh + (size_t)ZROW * F + (size_t)gt * 8) = z;  // zero row for tail lanes
  }
}

// ---------- half-wave-per-node aggregation over PRE-SCALED f16 rows ----------
// out[dst] = dinv[dst] * ( in'[dst] + sum_{src in bucket} in'[src] )
// Per edge: 1 bpermute (index) + 1 dwordx4 row-load + 8 v_fma_mix_f32.
// No per-edge cnt gather / rsqrt / weight shfl (folded into rows by producer).
// Next chunk's bucket indices are prefetched during current chunk's compute.
template <bool FUSE_MAX>
__global__ __launch_bounds__(256) void aggb_k(const _Float16* __restrict__ in,
                                              const int* __restrict__ cnt,
                                              const int* __restrict__ csr,
                                              const float* __restrict__ bias,
                                              _Float16* __restrict__ outh,
                                              float* __restrict__ out) {
  __shared__ float smem[2048];
  int tid = threadIdx.x;
  int lane = tid & 63, wvi = tid >> 6;
  int half = lane >> 5, hl = lane & 31;
  int f0 = hl * 8;
  int node = (blockIdx.x * 4 + wvi) * 2 + half;   // grid 1250 -> node < 10000
  float one = 1.0f;
  asm("" : "+v"(one));          // opaque 1.0 -> forces v_fma_mix_f32 (no cvt)
  floatx8 bb = {};
  if (FUSE_MAX) bb = *(const floatx8*)(bias + f0);

  int degfull = cnt[node];
  int deg = min(degfull, CAP);
  float di = rsqrtf((float)(degfull + 1));
  const int* bucket = csr + (size_t)node * CAP;
  const _Float16* inf = in + f0;

  half8 xsv = *(const half8*)(inf + (size_t)node * F);  // self row (pre-scaled)
  int sv = ZROW;
  if (hl < deg) sv = bucket[hl];                        // chunk-0 indices in flight

  floatx8 acc;
  #pragma unroll
  for (int t = 0; t < 8; t++) acc[t] = (float)xsv[t];   // self term

  for (int c = 0; c < deg; c += 32) {
    int mm = min(32, deg - c);
    // prefetch next chunk's indices (overlaps with compute below)
    int svn = ZROW;
    int rem = deg - c - 32;
    if (hl < rem) svn = bucket[c + 32 + hl];
    #pragma unroll
    for (int b = 0; b < 2; b++) {
      int base = b * 16;
      if (base < mm) {
        // phase 1: broadcast 16 indices (invalid lanes carry ZROW -> adds 0)
        int sj[16];
        #pragma unroll
        for (int u = 0; u < 16; u++) sj[u] = __shfl(sv, (half << 5) | (base + u), 64);
        // phase 2: 16 independent 16B row-loads (all issued before use)
        half8 hv[16];
        #pragma unroll
        for (int u = 0; u < 16; u++)
          hv[u] = *(const half8*)(inf + (size_t)sj[u] * F);
        // phase 3: unweighted accumulate via fma_mix (f16 src, f32 acc)
        #pragma unroll
        for (int u = 0; u < 16; u++)
          #pragma unroll
          for (int t = 0; t < 8; t++)
            acc[t] = __builtin_fmaf((float)hv[u][t], one, acc[t]);
      }
    }
    sv = svn;
  }

  if (FUSE_MAX) {
    floatx8 lmax;
    #pragma unroll
    for (int t = 0; t < 8; t++) lmax[t] = fmaxf(di * acc[t] + bb[t], 0.f);
    float* srow = smem + (size_t)(wvi * 2 + half) * 256;
    *(floatx8*)(srow + f0) = lmax;
    __syncthreads();
    float m = smem[tid];
    #pragma unroll
    for (int r = 1; r < 8; r++) m = fmaxf(m, smem[r * 256 + tid]);
    // relu outputs >= 0; out poison/zero is <= 0 as int -> atomicMax correct
    atomicMax((int*)&out[tid], __float_as_int(m));
  } else {
    floatx8 tot;
    #pragma unroll
    for (int t = 0; t < 8; t++) tot[t] = di * acc[t];
    *(half8*)(outh + (size_t)node * F + f0) = __builtin_convertvector(tot, half8);
  }
}

// ---------- fused GEMM1+GEMM2 per 32-row tile ----------
// h1(32x512) = relu(axh(32x256) @ W1t^T + b1)  staged in LDS
// xw2'(32x256) = dinv[row] * (h1 @ W2t^T)      -> global (pre-scaled for agg2)
// Padding rows (>= NNODES) get explicit 0 so the ZROW stays clean (no NaN).
__global__ __launch_bounds__(256) void gemm12_k(const _Float16* __restrict__ A,
                                                const _Float16* __restrict__ W1t,
                                                const float* __restrict__ b1,
                                                const _Float16* __restrict__ W2t,
                                                const float* __restrict__ dinv,
                                                _Float16* __restrict__ C) {
  __shared__ _Float16 h1[32 * H1STR];   // 32*520*2 = 33,280 B
  int lane = threadIdx.x & 63;
  int wv = threadIdx.x >> 6;
  int r = lane & 15, q = lane >> 4;
  int m0 = blockIdx.x * 32;

  // ---- phase 1: gemm1, wave wv covers cols [wv*128, wv*128+128) ----
  {
    floatx4 acc[2][8] = {};
    const _Float16* Ap = A + (size_t)(m0 + r) * F + q * 8;
    const _Float16* Bp = W1t + (size_t)(wv * 128 + r) * F + q * 8;
    for (int k0 = 0; k0 < F; k0 += 32) {
      half8 a[2], b[8];
      #pragma unroll
      for (int i = 0; i < 2; i++) a[i] = *(const half8*)(Ap + (size_t)i * 16 * F + k0);
      #pragma unroll
      for (int j = 0; j < 8; j++) b[j] = *(const half8*)(Bp + (size_t)j * 16 * F + k0);
      #pragma unroll
      for (int i = 0; i < 2; i++)
        #pragma unroll
        for (int j = 0; j < 8; j++)
          acc[i][j] = __builtin_amdgcn_mfma_f32_16x16x32_f16(a[i], b[j], acc[i][j], 0, 0, 0);
    }
    #pragma unroll
    for (int i = 0; i < 2; i++) {
      #pragma unroll
      for (int j = 0; j < 8; j++) {
        int n = wv * 128 + j * 16 + r;
        float bv = b1[n];
        #pragma unroll
        for (int rr = 0; rr < 4; rr++) {
          int row = i * 16 + q * 4 + rr;
          h1[row * H1STR + n] = (_Float16)fmaxf(acc[i][j][rr] + bv, 0.f);
        }
      }
    }
  }
  __syncthreads();

  // ---- phase 2: gemm2 from LDS h1, wave wv covers cols [wv*64, wv*64+64) ----
  {
    float sc[2][4];
    #pragma unroll
    for (int i = 0; i < 2; i++)
      #pragma unroll
      for (int rr = 0; rr < 4; rr++) {
        int row = m0 + i * 16 + q * 4 + rr;
        sc[i][rr] = (row < NNODES) ? dinv[row] : 0.f;
      }
    floatx4 acc[2][4] = {};
    const _Float16* Bp = W2t + (size_t)(wv * 64 + r) * H + q * 8;
    for (int k0 = 0; k0 < H; k0 += 32) {
      half8 a[2], b[4];
      #pragma unroll
      for (int i = 0; i < 2; i++)
        a[i] = *(const half8*)(h1 + (i * 16 + r) * H1STR + k0 + q * 8);
      #pragma unroll
      for (int j = 0; j < 4; j++) b[j] = *(const half8*)(Bp + (size_t)j * 16 * H + k0);
      #pragma unroll
      for (int i = 0; i < 2; i++)
        #pragma unroll
        for (int j = 0; j < 4; j++)
          acc[i][j] = __builtin_amdgcn_mfma_f32_16x16x32_f16(a[i], b[j], acc[i][j], 0, 0, 0);
    }
    #pragma unroll
    for (int i = 0; i < 2; i++) {
      #pragma unroll
      for (int j = 0; j < 4; j++) {
        int n = wv * 64 + j * 16 + r;
        #pragma unroll
        for (int rr = 0; rr < 4; rr++) {
          int row = m0 + i * 16 + q * 4 + rr;
          // explicit 0 (not acc*0) for padding rows: poison-NaN in A must not
          // reach the ZROW that aggb_k reads
          float val = (row < NNODES) ? acc[i][j][rr] * sc[i][rr] : 0.f;
          C[(size_t)row * F + n] = (_Float16)val;
        }
      }
    }
  }
}

extern "C" void kernel_launch(void* const* d_in, const int* in_sizes, int n_in,
                              void* d_out, int out_size, void* d_ws, size_t ws_size,
                              hipStream_t stream) {
  const float* x  = (const float*)d_in[0];
  const int*   ei = (const int*)d_in[1];
  const float* W1 = (const float*)d_in[2];
  const float* b1 = (const float*)d_in[3];
  const float* W2 = (const float*)d_in[4];
  const float* b2 = (const float*)d_in[5];
  const int E = in_sizes[1] / 2;
  const int N = NNODES;
  const int* src = ei;
  const int* dst = ei + E;

  char* w = (char*)d_ws;
  size_t off = 0;
  auto take = [&](size_t bytes) -> void* {
    void* p = w + off;
    off += (bytes + 255) & ~(size_t)255;
    return p;
  };
  int*       cnt    = (int*)take((size_t)N * 4);
  int*       csr    = (int*)take((size_t)N * CAP * 4);
  _Float16*  W1t    = (_Float16*)take((size_t)H * F * 2);
  _Float16*  W2t    = (_Float16*)take((size_t)F * H * 2);
  _Float16*  xh     = (_Float16*)take((size_t)(N + 1) * F * 2);  // +1: zero row
  float*     dinvp  = (float*)take((size_t)N * 4);
  _Float16*  axh    = (_Float16*)take((size_t)MP * F * 2);   // padded M
  _Float16*  xw2h   = (_Float16*)take((size_t)MP * F * 2);   // padded M (row ZROW = 0)

  zero_k<<<(N + 255) / 256, 256, 0, stream>>>(cnt);
  build_k<<<(E + 255) / 256, 256, 0, stream>>>(src, dst, cnt, csr, E);
  prep_k<<<1250, 256, 0, stream>>>(W1, W2, x, cnt, W1t, W2t, xh, dinvp);
  aggb_k<false><<<1250, 256, 0, stream>>>(xh, cnt, csr, nullptr, axh, nullptr);
  gemm12_k<<<MP / 32, 256, 0, stream>>>(axh, W1t, b1, W2t, dinvp, xw2h);
  aggb_k<true><<<1250, 256, 0, stream>>>(xw2h, cnt, csr, b2, nullptr, (float*)d_out);
}